// Round 4
// baseline (566.431 us; speedup 1.0000x reference)
//
#include <hip/hip_runtime.h>
#include <math.h>
#include <stdint.h>

#define NN 50000
#define NE 800000
#define HD 64
#define ECH 32
#define NHEAD 4
#define NBLK 196   // ceil(NN/256)

static_assert(NE % 256 == 0, "edge kernel assumes full blocks");

typedef __attribute__((ext_vector_type(8))) short bf8;
typedef __attribute__((ext_vector_type(4))) float f32x4;

__device__ __forceinline__ float ssp_f(float v) {
    return fmaxf(v, 0.0f) + log1pf(__expf(-fabsf(v))) - 0.69314718055994531f;
}
__device__ __forceinline__ uint32_t f2bf_bits(float f) {
    uint32_t u = __float_as_uint(f);
    return (u + 0x7FFFu + ((u >> 16) & 1u)) >> 16;
}
__device__ __forceinline__ float bf2f(uint32_t b) { return __uint_as_float(b << 16); }

__device__ __forceinline__ void unpack8(uint4 p, float* o) {
    o[0] = bf2f(p.x & 0xffffu); o[1] = bf2f(p.x >> 16);
    o[2] = bf2f(p.y & 0xffffu); o[3] = bf2f(p.y >> 16);
    o[4] = bf2f(p.z & 0xffffu); o[5] = bf2f(p.z >> 16);
    o[6] = bf2f(p.w & 0xffffu); o[7] = bf2f(p.w >> 16);
}
__device__ __forceinline__ uint4 pack8u(const float* s) {
    uint4 r;
    r.x = f2bf_bits(s[0]) | (f2bf_bits(s[1]) << 16);
    r.y = f2bf_bits(s[2]) | (f2bf_bits(s[3]) << 16);
    r.z = f2bf_bits(s[4]) | (f2bf_bits(s[5]) << 16);
    r.w = f2bf_bits(s[6]) | (f2bf_bits(s[7]) << 16);
    return r;
}
__device__ __forceinline__ bf8 pack_bf8(float4 a, float4 b) {
    bf8 r;
    r[0] = (short)f2bf_bits(a.x); r[1] = (short)f2bf_bits(a.y);
    r[2] = (short)f2bf_bits(a.z); r[3] = (short)f2bf_bits(a.w);
    r[4] = (short)f2bf_bits(b.x); r[5] = (short)f2bf_bits(b.y);
    r[6] = (short)f2bf_bits(b.z); r[7] = (short)f2bf_bits(b.w);
    return r;
}
__device__ __forceinline__ bf8 zero_bf8() {
    bf8 r;
    #pragma unroll
    for (int i = 0; i < 8; ++i) r[i] = 0;
    return r;
}

// ---------------- Kernel A: node q/k/v, fold wkl into q side, bf16 outputs ----------------
__global__ __launch_bounds__(256) void node_transform_kernel(
    const float* __restrict__ x,
    const float* __restrict__ k_w, const float* __restrict__ q_w, const float* __restrict__ v_w,
    const float* __restrict__ wkl_w, const float* __restrict__ wkl_b,
    uint16_t* __restrict__ qt, float* __restrict__ qb,
    uint16_t* __restrict__ hk, uint16_t* __restrict__ hv)
{
    __shared__ float skw[NHEAD * 256], sqw[NHEAD * 256], svw[NHEAD * 256];
    __shared__ float s_kl[256], s_klb[16];
    for (int i = threadIdx.x; i < NHEAD * 256; i += 256) {
        skw[i] = k_w[i]; sqw[i] = q_w[i]; svw[i] = v_w[i];
    }
    if (threadIdx.x < 256) s_kl[threadIdx.x] = wkl_w[threadIdx.x];
    if (threadIdx.x < 16) s_klb[threadIdx.x] = wkl_b[threadIdx.x];
    __syncthreads();
    int n = blockIdx.x * 256 + threadIdx.x;
    if (n >= NN) return;
    const float* xn = x + (size_t)n * HD;
    float qbv[NHEAD];
    for (int h = 0; h < NHEAD; ++h) {
        float xr[16];
        {
            const float4* xp = (const float4*)(xn + h * 16);
            #pragma unroll
            for (int j = 0; j < 4; ++j) *(float4*)&xr[4 * j] = xp[j];
        }
        float rq[16], rk[16], rv[16];
        for (int o = 0; o < 16; ++o) {
            const float* wq = sqw + h * 256 + o * 16;
            const float* wk = skw + h * 256 + o * 16;
            const float* wv = svw + h * 256 + o * 16;
            float sq = 0.f, sk = 0.f, sv = 0.f;
            #pragma unroll
            for (int i = 0; i < 16; ++i) {
                sq += xr[i] * wq[i];
                sk += xr[i] * wk[i];
                sv += xr[i] * wv[i];
            }
            rq[o] = sq; rk[o] = sk; rv[o] = sv;
        }
        float rqt[16];
        float qbh = 0.f;
        for (int i = 0; i < 16; ++i) {
            float s = 0.f;
            #pragma unroll
            for (int o = 0; o < 16; ++o) s += rq[o] * s_kl[o * 16 + i];
            rqt[i] = s;
        }
        #pragma unroll
        for (int o = 0; o < 16; ++o) qbh += rq[o] * s_klb[o];
        qbv[h] = qbh;

        uint4* oq = (uint4*)(qt + (size_t)n * HD + h * 16);
        uint4* ok = (uint4*)(hk + (size_t)n * HD + h * 16);
        uint4* ov = (uint4*)(hv + (size_t)n * HD + h * 16);
        oq[0] = pack8u(rqt); oq[1] = pack8u(rqt + 8);
        ok[0] = pack8u(rk);  ok[1] = pack8u(rk + 8);
        ov[0] = pack8u(rv);  ov[1] = pack8u(rv + 8);
    }
    *(float4*)(qb + (size_t)n * NHEAD) = *(float4*)&qbv[0];
}

// ---------------- Count rows ----------------
__global__ __launch_bounds__(256) void count_kernel(
    const int* __restrict__ ei, int* __restrict__ counts)
{
    int e = blockIdx.x * 256 + threadIdx.x;
    if (e >= NE) return;
    atomicAdd(counts + ei[e], 1);
}

// ---------------- Hierarchical scan ----------------
__global__ __launch_bounds__(256) void scan_bsum_kernel(
    const int* __restrict__ counts, int* __restrict__ bsum)
{
    __shared__ int sd[256];
    int i = blockIdx.x * 256 + threadIdx.x;
    sd[threadIdx.x] = (i < NN) ? counts[i] : 0;
    __syncthreads();
    for (int s = 128; s > 0; s >>= 1) {
        if (threadIdx.x < (unsigned)s) sd[threadIdx.x] += sd[threadIdx.x + s];
        __syncthreads();
    }
    if (threadIdx.x == 0) bsum[blockIdx.x] = sd[0];
}

__global__ __launch_bounds__(256) void scan_top_kernel(int* __restrict__ bsum)
{
    __shared__ int tmp[256];
    int v = (threadIdx.x < NBLK) ? bsum[threadIdx.x] : 0;
    tmp[threadIdx.x] = v;
    __syncthreads();
    for (int d = 1; d < 256; d <<= 1) {
        int t = (threadIdx.x >= (unsigned)d) ? tmp[threadIdx.x - d] : 0;
        __syncthreads();
        tmp[threadIdx.x] += t;
        __syncthreads();
    }
    if (threadIdx.x < NBLK) bsum[threadIdx.x] = tmp[threadIdx.x] - v;  // exclusive
}

__global__ __launch_bounds__(256) void scan_final_kernel(
    const int* __restrict__ counts, const int* __restrict__ bsum,
    int* __restrict__ offsets, int* __restrict__ cursor)
{
    __shared__ int tmp[256];
    int i = blockIdx.x * 256 + threadIdx.x;
    int v = (i < NN) ? counts[i] : 0;
    tmp[threadIdx.x] = v;
    __syncthreads();
    for (int d = 1; d < 256; d <<= 1) {
        int t = (threadIdx.x >= (unsigned)d) ? tmp[threadIdx.x - d] : 0;
        __syncthreads();
        tmp[threadIdx.x] += t;
        __syncthreads();
    }
    int excl = tmp[threadIdx.x] - v + bsum[blockIdx.x];
    if (i < NN) { offsets[i] = excl; cursor[i] = excl; }
}

// ---------------- Scatter: edge ids + (row,col) into CSR order ----------------
__global__ __launch_bounds__(256) void scatter_kernel(
    const int* __restrict__ ei, int* __restrict__ cursor,
    int* __restrict__ elist, int2* __restrict__ rc)
{
    int e = blockIdx.x * 256 + threadIdx.x;
    if (e >= NE) return;
    int r = ei[e];
    int c = ei[NE + e];
    int pos = atomicAdd(cursor + r, 1);
    elist[pos] = e;
    rc[pos] = make_int2(r, c);
}

// ---------------- Kernel B: edge compute, MFMA MLPs, CSR-ordered coalesced writes ----------------
__global__ __launch_bounds__(256) void edge_compute_kernel(
    const int* __restrict__ elist, const int2* __restrict__ rc,
    const float* __restrict__ ea,
    const float* __restrict__ wkn_w1, const float* __restrict__ wkn_b1,
    const float* __restrict__ wkn_w2, const float* __restrict__ wkn_b2,
    const float* __restrict__ wvn_w1, const float* __restrict__ wvn_b1,
    const float* __restrict__ wvn_w2, const float* __restrict__ wvn_b2,
    const uint16_t* __restrict__ qt, const float* __restrict__ qb,
    const uint16_t* __restrict__ hk, const uint16_t* __restrict__ hv,
    uint16_t* __restrict__ payload, float* __restrict__ wfac)
{
    // per-wave private LDS: layer1 scratch + Wk/Wv transposes (bf16, rows padded to 24)
    __shared__ uint16_t s_tr1[4][64][24];
    __shared__ uint16_t s_trk[4][64][24];
    __shared__ uint16_t s_trv[4][64][24];

    const int w = threadIdx.x >> 6;
    const int L = threadIdx.x & 63;
    const int m = L & 15;     // A: out-channel, B: edge-within-tile, D: col=edge
    const int g = L >> 4;     // k-group (A/B), row-quad (D)
    const int ebase = blockIdx.x * 256 + w * 64;

    // --- stage edge_attr B-fragments: B[k=8g+j][n=m] = ea[edge 16t+m][8g+j] ---
    bf8 eaf[4];
    #pragma unroll
    for (int t = 0; t < 4; ++t) {
        int eid = elist[ebase + 16 * t + m];
        const float* er = ea + (size_t)eid * ECH + 8 * g;
        eaf[t] = pack_bf8(*(const float4*)er, *(const float4*)(er + 4));
    }
    // --- weight A-fragments: A[m=o][k] = w[o][k] ---
    bf8 w1kf, w1vf, w2kf, w2vf;
    {
        const float* p = wkn_w1 + m * 32 + 8 * g;
        w1kf = pack_bf8(*(const float4*)p, *(const float4*)(p + 4));
        p = wvn_w1 + m * 32 + 8 * g;
        w1vf = pack_bf8(*(const float4*)p, *(const float4*)(p + 4));
        if (g < 2) {
            p = wkn_w2 + m * 16 + 8 * g;
            w2kf = pack_bf8(*(const float4*)p, *(const float4*)(p + 4));
            p = wvn_w2 + m * 16 + 8 * g;
            w2vf = pack_bf8(*(const float4*)p, *(const float4*)(p + 4));
        } else {
            w2kf = zero_bf8(); w2vf = zero_bf8();
        }
    }
    float4 b1k = *(const float4*)(wkn_b1 + 4 * g);
    float4 b1v = *(const float4*)(wvn_b1 + 4 * g);
    float4 b2k = *(const float4*)(wkn_b2 + 4 * g);
    float4 b2v = *(const float4*)(wvn_b2 + 4 * g);

    // --- layer1 k-net: D[o=4g+r][e=16t+m]; +bias via C; ssp; LDS transpose ---
    #pragma unroll
    for (int t = 0; t < 4; ++t) {
        f32x4 acc = {b1k.x, b1k.y, b1k.z, b1k.w};
        acc = __builtin_amdgcn_mfma_f32_16x16x32_bf16(w1kf, eaf[t], acc, 0, 0, 0);
        uint2 pk;
        pk.x = f2bf_bits(ssp_f(acc[0])) | (f2bf_bits(ssp_f(acc[1])) << 16);
        pk.y = f2bf_bits(ssp_f(acc[2])) | (f2bf_bits(ssp_f(acc[3])) << 16);
        *(uint2*)&s_tr1[w][16 * t + m][4 * g] = pk;
    }
    __syncthreads();
    bf8 l1k[4];
    #pragma unroll
    for (int t = 0; t < 4; ++t)
        l1k[t] = (g < 2) ? *(const bf8*)&s_tr1[w][16 * t + m][8 * g] : zero_bf8();
    __syncthreads();
    // --- layer1 v-net (reuse scratch) ---
    #pragma unroll
    for (int t = 0; t < 4; ++t) {
        f32x4 acc = {b1v.x, b1v.y, b1v.z, b1v.w};
        acc = __builtin_amdgcn_mfma_f32_16x16x32_bf16(w1vf, eaf[t], acc, 0, 0, 0);
        uint2 pk;
        pk.x = f2bf_bits(ssp_f(acc[0])) | (f2bf_bits(ssp_f(acc[1])) << 16);
        pk.y = f2bf_bits(ssp_f(acc[2])) | (f2bf_bits(ssp_f(acc[3])) << 16);
        *(uint2*)&s_tr1[w][16 * t + m][4 * g] = pk;
    }
    __syncthreads();
    bf8 l1v[4];
    #pragma unroll
    for (int t = 0; t < 4; ++t)
        l1v[t] = (g < 2) ? *(const bf8*)&s_tr1[w][16 * t + m][8 * g] : zero_bf8();

    // --- layer2 (K=16 zero-padded to 32): Wk/Wv[o=4g+r][e=16t+m] -> LDS ---
    #pragma unroll
    for (int t = 0; t < 4; ++t) {
        f32x4 acc = {b2k.x, b2k.y, b2k.z, b2k.w};
        acc = __builtin_amdgcn_mfma_f32_16x16x32_bf16(w2kf, l1k[t], acc, 0, 0, 0);
        uint2 pk;
        pk.x = f2bf_bits(acc[0]) | (f2bf_bits(acc[1]) << 16);
        pk.y = f2bf_bits(acc[2]) | (f2bf_bits(acc[3]) << 16);
        *(uint2*)&s_trk[w][16 * t + m][4 * g] = pk;

        f32x4 accv = {b2v.x, b2v.y, b2v.z, b2v.w};
        accv = __builtin_amdgcn_mfma_f32_16x16x32_bf16(w2vf, l1v[t], accv, 0, 0, 0);
        uint2 pv;
        pv.x = f2bf_bits(accv[0]) | (f2bf_bits(accv[1]) << 16);
        pv.y = f2bf_bits(accv[2]) | (f2bf_bits(accv[3]) << 16);
        *(uint2*)&s_trv[w][16 * t + m][4 * g] = pv;
    }
    __syncthreads();

    // --- per-edge tail: lane L owns sorted position E = ebase + L ---
    const int E = ebase + L;
    int2 rcv = rc[E];
    const int row = rcv.x, col = rcv.y;

    float Wk[16], Wv[16];
    unpack8(*(const uint4*)&s_trk[w][L][0], Wk);
    unpack8(*(const uint4*)&s_trk[w][L][8], Wk + 8);
    unpack8(*(const uint4*)&s_trv[w][L][0], Wv);
    unpack8(*(const uint4*)&s_trv[w][L][8], Wv + 8);

    float4 qbv = *(const float4*)(qb + (size_t)row * NHEAD);
    const float qbarr[4] = {qbv.x, qbv.y, qbv.z, qbv.w};
    const uint4* qtb = (const uint4*)(qt + (size_t)row * HD);
    const uint4* kb  = (const uint4*)(hk + (size_t)col * HD);
    const uint4* vb  = (const uint4*)(hv + (size_t)col * HD);
    uint4* pd = (uint4*)(payload + (size_t)E * HD);
    float wf[NHEAD];

    #pragma unroll
    for (int h = 0; h < NHEAD; ++h) {
        float qr[16], kc[16], vc[16];
        unpack8(qtb[2 * h], qr); unpack8(qtb[2 * h + 1], qr + 8);
        unpack8(kb[2 * h], kc);  unpack8(kb[2 * h + 1], kc + 8);
        unpack8(vb[2 * h], vc);  unpack8(vb[2 * h + 1], vc + 8);
        float qk = qbarr[h];
        #pragma unroll
        for (int i = 0; i < 16; ++i) qk += qr[i] * Wk[i] * kc[i];
        float wgt = __expf(qk);   // softmax shift-invariance
        wf[h] = wgt;
        float o0[8], o1[8];
        #pragma unroll
        for (int i = 0; i < 8; ++i) o0[i] = wgt * Wv[i] * vc[i];
        #pragma unroll
        for (int i = 0; i < 8; ++i) o1[i] = wgt * Wv[8 + i] * vc[8 + i];
        pd[2 * h]     = pack8u(o0);
        pd[2 * h + 1] = pack8u(o1);
    }
    *(float4*)(wfac + (size_t)E * NHEAD) = *(float4*)&wf[0];
}

// ---------------- Kernel E: streaming gather + normalize + wvl + cen + ssp + out ----------------
__global__ __launch_bounds__(256) void gather_finalize_kernel(
    const float* __restrict__ x,
    const uint16_t* __restrict__ payload, const float* __restrict__ wfac,
    const int* __restrict__ offsets, const int* __restrict__ counts,
    const float* __restrict__ wvl_w, const float* __restrict__ wvl_b,
    const float* __restrict__ cen_w, const float* __restrict__ cen_b,
    const float* __restrict__ out_w, const float* __restrict__ out_b,
    float* __restrict__ out)
{
    __shared__ float s_cw[4096], s_ow[4096];
    __shared__ float s_wvl[256], s_vlb[16];
    __shared__ float s_m[4][64], s_x[4][64], s_t[4][64];
    for (int idx = threadIdx.x; idx < 4096; idx += 256) {
        int o = idx & 63, i = idx >> 6;
        s_cw[i * 64 + o] = cen_w[o * 64 + i];
        s_ow[i * 64 + o] = out_w[o * 64 + i];
    }
    if (threadIdx.x < 256) s_wvl[threadIdx.x] = wvl_w[threadIdx.x];
    if (threadIdx.x < 16) s_vlb[threadIdx.x] = wvl_b[threadIdx.x];
    __syncthreads();

    int l = threadIdx.x >> 6;
    int L = threadIdx.x & 63;
    int q = L & 15, g = L >> 4;
    int head4 = q >> 2;

    for (int t = 0; t < 4; ++t) {
        int n = blockIdx.x * 16 + l * 4 + t;
        bool valid = n < NN;
        int st = 0, deg = 0;
        if (valid) { st = offsets[n]; deg = counts[n]; }
        float u0 = 0.f, u1 = 0.f, u2 = 0.f, u3 = 0.f, ds = 0.f;
        const uint16_t* pp = payload + (size_t)st * HD + 4 * q;
        const float* wp = wfac + (size_t)st * NHEAD + head4;
        int iters = (deg + 3) >> 2;
        for (int i = 0; i < iters; ++i) {
            int e = i * 4 + g;
            if (e < deg) {
                uint2 pv = *(const uint2*)(pp + (size_t)e * HD);
                u0 += bf2f(pv.x & 0xffffu); u1 += bf2f(pv.x >> 16);
                u2 += bf2f(pv.y & 0xffffu); u3 += bf2f(pv.y >> 16);
                ds += wp[(size_t)e * NHEAD];
            }
        }
        u0 += __shfl_xor(u0, 16); u1 += __shfl_xor(u1, 16);
        u2 += __shfl_xor(u2, 16); u3 += __shfl_xor(u3, 16);
        ds += __shfl_xor(ds, 16);
        u0 += __shfl_xor(u0, 32); u1 += __shfl_xor(u1, 32);
        u2 += __shfl_xor(u2, 32); u3 += __shfl_xor(u3, 32);
        ds += __shfl_xor(ds, 32);

        float m0 = 0.f, m1 = 0.f, m2 = 0.f, m3 = 0.f;
        if (deg > 0) {
            float inv = 1.f / ds;
            m0 = u0 * inv; m1 = u1 * inv; m2 = u2 * inv; m3 = u3 * inv;
        }
        float msel = (g == 0) ? m0 : (g == 1) ? m1 : (g == 2) ? m2 : m3;
        s_m[l][4 * q + g] = msel;
        s_x[l][L] = valid ? x[(size_t)n * HD + L] : 0.f;

        int c = L, h = c >> 4;
        float aggr = 0.f;
        if (deg > 0) {
            int o = c & 15;
            float s = s_vlb[o];
            #pragma unroll
            for (int i = 0; i < 16; ++i) s += s_m[l][h * 16 + i] * s_wvl[o * 16 + i];
            aggr = s;
        }
        float sc = cen_b[c];
        #pragma unroll 8
        for (int i = 0; i < 64; ++i) sc += s_x[l][i] * s_cw[i * 64 + c];
        sc += aggr;
        s_t[l][c] = ssp_f(sc);
        float so = out_b[c];
        #pragma unroll 8
        for (int i = 0; i < 64; ++i) so += s_t[l][i] * s_ow[i * 64 + c];
        if (valid) out[(size_t)n * HD + c] = so;
    }
}

extern "C" void kernel_launch(void* const* d_in, const int* in_sizes, int n_in,
                              void* d_out, int out_size, void* d_ws, size_t ws_size,
                              hipStream_t stream)
{
    const float* x      = (const float*)d_in[0];
    const int*   ei     = (const int*)d_in[1];
    const float* ea     = (const float*)d_in[2];
    const float* k_w    = (const float*)d_in[3];
    const float* q_w    = (const float*)d_in[4];
    const float* v_w    = (const float*)d_in[5];
    const float* wkn_w1 = (const float*)d_in[6];
    const float* wkn_b1 = (const float*)d_in[7];
    const float* wkn_w2 = (const float*)d_in[8];
    const float* wkn_b2 = (const float*)d_in[9];
    const float* wkl_w  = (const float*)d_in[10];
    const float* wkl_b  = (const float*)d_in[11];
    const float* wvn_w1 = (const float*)d_in[12];
    const float* wvn_b1 = (const float*)d_in[13];
    const float* wvn_w2 = (const float*)d_in[14];
    const float* wvn_b2 = (const float*)d_in[15];
    const float* wvl_w  = (const float*)d_in[16];
    const float* wvl_b  = (const float*)d_in[17];
    const float* cen_w  = (const float*)d_in[18];
    const float* cen_b  = (const float*)d_in[19];
    const float* out_w  = (const float*)d_in[20];
    const float* out_b  = (const float*)d_in[21];
    float* out = (float*)d_out;

    // workspace layout
    float* qb    = (float*)d_ws;                              // NN*4 f32
    float* wfac  = qb + (size_t)NN * NHEAD;                   // NE*4 f32
    uint16_t* qt = (uint16_t*)(wfac + (size_t)NE * NHEAD);    // NN*64 bf16
    uint16_t* hk = qt + (size_t)NN * HD;                      // NN*64 bf16
    uint16_t* hv = hk + (size_t)NN * HD;                      // NN*64 bf16
    uint16_t* payload = hv + (size_t)NN * HD;                 // NE*64 bf16
    int2* rc     = (int2*)(payload + (size_t)NE * HD);        // NE int2
    int* elist   = (int*)(rc + (size_t)NE);                   // NE
    int* counts  = elist + NE;                                // NN
    int* bsum    = counts + NN;                               // 256
    int* offsets = bsum + 256;                                // NN
    int* cursor  = offsets + NN;                              // NN

    hipMemsetAsync(counts, 0, (size_t)NN * sizeof(int), stream);
    node_transform_kernel<<<NBLK, 256, 0, stream>>>(
        x, k_w, q_w, v_w, wkl_w, wkl_b, qt, qb, hk, hv);
    count_kernel<<<(NE + 255) / 256, 256, 0, stream>>>(ei, counts);
    scan_bsum_kernel<<<NBLK, 256, 0, stream>>>(counts, bsum);
    scan_top_kernel<<<1, 256, 0, stream>>>(bsum);
    scan_final_kernel<<<NBLK, 256, 0, stream>>>(counts, bsum, offsets, cursor);
    scatter_kernel<<<(NE + 255) / 256, 256, 0, stream>>>(ei, cursor, elist, rc);
    edge_compute_kernel<<<NE / 256, 256, 0, stream>>>(
        elist, rc, ea, wkn_w1, wkn_b1, wkn_w2, wkn_b2,
        wvn_w1, wvn_b1, wvn_w2, wvn_b2,
        qt, qb, hk, hv, payload, wfac);
    gather_finalize_kernel<<<(NN + 15) / 16, 256, 0, stream>>>(
        x, payload, wfac, offsets, counts,
        wvl_w, wvl_b, cen_w, cen_b, out_w, out_b, out);
}

// Round 5
// 516.709 us; speedup vs baseline: 1.0962x; 1.0962x over previous
//
#include <hip/hip_runtime.h>
#include <math.h>
#include <stdint.h>

#define NN 50000
#define NE 800000
#define HD 64
#define ECH 32
#define NHEAD 4
#define NBLK 196   // ceil(NN/256)

static_assert(NE % 256 == 0, "edge kernel assumes full blocks");

typedef __attribute__((ext_vector_type(8))) short bf8;
typedef __attribute__((ext_vector_type(4))) float f32x4;

__device__ __forceinline__ float ssp_f(float v) {
    return fmaxf(v, 0.0f) + log1pf(__expf(-fabsf(v))) - 0.69314718055994531f;
}
__device__ __forceinline__ uint32_t f2bf_bits(float f) {
    uint32_t u = __float_as_uint(f);
    return (u + 0x7FFFu + ((u >> 16) & 1u)) >> 16;
}
__device__ __forceinline__ float bf2f(uint32_t b) { return __uint_as_float(b << 16); }

__device__ __forceinline__ void unpack8(uint4 p, float* o) {
    o[0] = bf2f(p.x & 0xffffu); o[1] = bf2f(p.x >> 16);
    o[2] = bf2f(p.y & 0xffffu); o[3] = bf2f(p.y >> 16);
    o[4] = bf2f(p.z & 0xffffu); o[5] = bf2f(p.z >> 16);
    o[6] = bf2f(p.w & 0xffffu); o[7] = bf2f(p.w >> 16);
}
__device__ __forceinline__ uint4 pack8u(const float* s) {
    uint4 r;
    r.x = f2bf_bits(s[0]) | (f2bf_bits(s[1]) << 16);
    r.y = f2bf_bits(s[2]) | (f2bf_bits(s[3]) << 16);
    r.z = f2bf_bits(s[4]) | (f2bf_bits(s[5]) << 16);
    r.w = f2bf_bits(s[6]) | (f2bf_bits(s[7]) << 16);
    return r;
}
__device__ __forceinline__ bf8 pack_bf8(float4 a, float4 b) {
    bf8 r;
    r[0] = (short)f2bf_bits(a.x); r[1] = (short)f2bf_bits(a.y);
    r[2] = (short)f2bf_bits(a.z); r[3] = (short)f2bf_bits(a.w);
    r[4] = (short)f2bf_bits(b.x); r[5] = (short)f2bf_bits(b.y);
    r[6] = (short)f2bf_bits(b.z); r[7] = (short)f2bf_bits(b.w);
    return r;
}
__device__ __forceinline__ bf8 zero_bf8() {
    bf8 r;
    #pragma unroll
    for (int i = 0; i < 8; ++i) r[i] = 0;
    return r;
}

// ---------------- Kernel A: node q/k/v, fold wkl into q side, bf16 outputs ----------------
__global__ __launch_bounds__(256) void node_transform_kernel(
    const float* __restrict__ x,
    const float* __restrict__ k_w, const float* __restrict__ q_w, const float* __restrict__ v_w,
    const float* __restrict__ wkl_w, const float* __restrict__ wkl_b,
    uint16_t* __restrict__ qt, float* __restrict__ qb,
    uint16_t* __restrict__ hk, uint16_t* __restrict__ hv)
{
    __shared__ float skw[NHEAD * 256], sqw[NHEAD * 256], svw[NHEAD * 256];
    __shared__ float s_kl[256], s_klb[16];
    for (int i = threadIdx.x; i < NHEAD * 256; i += 256) {
        skw[i] = k_w[i]; sqw[i] = q_w[i]; svw[i] = v_w[i];
    }
    if (threadIdx.x < 256) s_kl[threadIdx.x] = wkl_w[threadIdx.x];
    if (threadIdx.x < 16) s_klb[threadIdx.x] = wkl_b[threadIdx.x];
    __syncthreads();
    int n = blockIdx.x * 256 + threadIdx.x;
    if (n >= NN) return;
    const float* xn = x + (size_t)n * HD;
    float qbv[NHEAD];
    for (int h = 0; h < NHEAD; ++h) {
        float xr[16];
        {
            const float4* xp = (const float4*)(xn + h * 16);
            #pragma unroll
            for (int j = 0; j < 4; ++j) *(float4*)&xr[4 * j] = xp[j];
        }
        float rq[16], rk[16], rv[16];
        for (int o = 0; o < 16; ++o) {
            const float* wq = sqw + h * 256 + o * 16;
            const float* wk = skw + h * 256 + o * 16;
            const float* wv = svw + h * 256 + o * 16;
            float sq = 0.f, sk = 0.f, sv = 0.f;
            #pragma unroll
            for (int i = 0; i < 16; ++i) {
                sq += xr[i] * wq[i];
                sk += xr[i] * wk[i];
                sv += xr[i] * wv[i];
            }
            rq[o] = sq; rk[o] = sk; rv[o] = sv;
        }
        float rqt[16];
        float qbh = 0.f;
        for (int i = 0; i < 16; ++i) {
            float s = 0.f;
            #pragma unroll
            for (int o = 0; o < 16; ++o) s += rq[o] * s_kl[o * 16 + i];
            rqt[i] = s;
        }
        #pragma unroll
        for (int o = 0; o < 16; ++o) qbh += rq[o] * s_klb[o];
        qbv[h] = qbh;

        uint4* oq = (uint4*)(qt + (size_t)n * HD + h * 16);
        uint4* ok = (uint4*)(hk + (size_t)n * HD + h * 16);
        uint4* ov = (uint4*)(hv + (size_t)n * HD + h * 16);
        oq[0] = pack8u(rqt); oq[1] = pack8u(rqt + 8);
        ok[0] = pack8u(rk);  ok[1] = pack8u(rk + 8);
        ov[0] = pack8u(rv);  ov[1] = pack8u(rv + 8);
    }
    *(float4*)(qb + (size_t)n * NHEAD) = *(float4*)&qbv[0];
}

// ---------------- Count rows ----------------
__global__ __launch_bounds__(256) void count_kernel(
    const int* __restrict__ ei, int* __restrict__ counts)
{
    int e = blockIdx.x * 256 + threadIdx.x;
    if (e >= NE) return;
    atomicAdd(counts + ei[e], 1);
}

// ---------------- Hierarchical scan ----------------
__global__ __launch_bounds__(256) void scan_bsum_kernel(
    const int* __restrict__ counts, int* __restrict__ bsum)
{
    __shared__ int sd[256];
    int i = blockIdx.x * 256 + threadIdx.x;
    sd[threadIdx.x] = (i < NN) ? counts[i] : 0;
    __syncthreads();
    for (int s = 128; s > 0; s >>= 1) {
        if (threadIdx.x < (unsigned)s) sd[threadIdx.x] += sd[threadIdx.x + s];
        __syncthreads();
    }
    if (threadIdx.x == 0) bsum[blockIdx.x] = sd[0];
}

__global__ __launch_bounds__(256) void scan_top_kernel(int* __restrict__ bsum)
{
    __shared__ int tmp[256];
    int v = (threadIdx.x < NBLK) ? bsum[threadIdx.x] : 0;
    tmp[threadIdx.x] = v;
    __syncthreads();
    for (int d = 1; d < 256; d <<= 1) {
        int t = (threadIdx.x >= (unsigned)d) ? tmp[threadIdx.x - d] : 0;
        __syncthreads();
        tmp[threadIdx.x] += t;
        __syncthreads();
    }
    if (threadIdx.x < NBLK) bsum[threadIdx.x] = tmp[threadIdx.x] - v;  // exclusive
}

__global__ __launch_bounds__(256) void scan_final_kernel(
    const int* __restrict__ counts, const int* __restrict__ bsum,
    int* __restrict__ offsets, int* __restrict__ cursor)
{
    __shared__ int tmp[256];
    int i = blockIdx.x * 256 + threadIdx.x;
    int v = (i < NN) ? counts[i] : 0;
    tmp[threadIdx.x] = v;
    __syncthreads();
    for (int d = 1; d < 256; d <<= 1) {
        int t = (threadIdx.x >= (unsigned)d) ? tmp[threadIdx.x - d] : 0;
        __syncthreads();
        tmp[threadIdx.x] += t;
        __syncthreads();
    }
    int excl = tmp[threadIdx.x] - v + bsum[blockIdx.x];
    if (i < NN) { offsets[i] = excl; cursor[i] = excl; }
}

// ---------------- Scatter: edge ids + (row,col) into CSR order ----------------
__global__ __launch_bounds__(256) void scatter_kernel(
    const int* __restrict__ ei, int* __restrict__ cursor,
    int* __restrict__ elist, int2* __restrict__ rc)
{
    int e = blockIdx.x * 256 + threadIdx.x;
    if (e >= NE) return;
    int r = ei[e];
    int c = ei[NE + e];
    int pos = atomicAdd(cursor + r, 1);
    elist[pos] = e;
    rc[pos] = make_int2(r, c);
}

// ---------------- Kernel B: edge compute, MFMA MLPs, 4-lanes-per-edge tail ----------------
__global__ __launch_bounds__(256) void edge_compute_kernel(
    const int* __restrict__ elist, const int2* __restrict__ rc,
    const float* __restrict__ ea,
    const float* __restrict__ wkn_w1, const float* __restrict__ wkn_b1,
    const float* __restrict__ wkn_w2, const float* __restrict__ wkn_b2,
    const float* __restrict__ wvn_w1, const float* __restrict__ wvn_b1,
    const float* __restrict__ wvn_w2, const float* __restrict__ wvn_b2,
    const uint16_t* __restrict__ qt, const float* __restrict__ qb,
    const uint16_t* __restrict__ hk, const uint16_t* __restrict__ hv,
    uint16_t* __restrict__ payload, float* __restrict__ wfac)
{
    // per-wave PRIVATE LDS (indexed by w): no __syncthreads needed anywhere —
    // same-wave ds_write -> ds_read ordering (validated by gather kernel since R3).
    // rows padded to 24 (48B stride: keeps 16B alignment for b128 reads, 2-way banks = free)
    __shared__ uint16_t s_tr1[4][64][24];
    __shared__ uint16_t s_trk[4][64][24];
    __shared__ uint16_t s_trv[4][64][24];

    const int w = threadIdx.x >> 6;
    const int L = threadIdx.x & 63;
    const int m = L & 15;     // MFMA: A out-ch / B edge / D col=edge; tail: edge-within-tile
    const int g = L >> 4;     // MFMA: k-group / D row-quad; tail: head = channel-chunk
    const int ebase = blockIdx.x * 256 + w * 64;

    // prefetch row/col for the 4 tail tiles (independent of MFMA front)
    int2 rcv[4];
    #pragma unroll
    for (int t = 0; t < 4; ++t) rcv[t] = rc[ebase + 16 * t + m];

    // --- stage edge_attr B-fragments: B[k=8g+j][n=m] = ea[edge 16t+m][8g+j] ---
    bf8 eaf[4];
    #pragma unroll
    for (int t = 0; t < 4; ++t) {
        int eid = elist[ebase + 16 * t + m];
        const float* er = ea + (size_t)eid * ECH + 8 * g;
        eaf[t] = pack_bf8(*(const float4*)er, *(const float4*)(er + 4));
    }
    // --- weight A-fragments: A[m=o][k] = w[o][k] ---
    bf8 w1kf, w1vf, w2kf, w2vf;
    {
        const float* p = wkn_w1 + m * 32 + 8 * g;
        w1kf = pack_bf8(*(const float4*)p, *(const float4*)(p + 4));
        p = wvn_w1 + m * 32 + 8 * g;
        w1vf = pack_bf8(*(const float4*)p, *(const float4*)(p + 4));
        if (g < 2) {
            p = wkn_w2 + m * 16 + 8 * g;
            w2kf = pack_bf8(*(const float4*)p, *(const float4*)(p + 4));
            p = wvn_w2 + m * 16 + 8 * g;
            w2vf = pack_bf8(*(const float4*)p, *(const float4*)(p + 4));
        } else {
            w2kf = zero_bf8(); w2vf = zero_bf8();
        }
    }
    float4 b1k = *(const float4*)(wkn_b1 + 4 * g);
    float4 b1v = *(const float4*)(wvn_b1 + 4 * g);
    float4 b2k = *(const float4*)(wkn_b2 + 4 * g);
    float4 b2v = *(const float4*)(wvn_b2 + 4 * g);

    // --- layer1 k-net: D[o=4g+r][e=16t+m]; bias via C; ssp; per-wave LDS transpose ---
    #pragma unroll
    for (int t = 0; t < 4; ++t) {
        f32x4 acc = {b1k.x, b1k.y, b1k.z, b1k.w};
        acc = __builtin_amdgcn_mfma_f32_16x16x32_bf16(w1kf, eaf[t], acc, 0, 0, 0);
        uint2 pk;
        pk.x = f2bf_bits(ssp_f(acc[0])) | (f2bf_bits(ssp_f(acc[1])) << 16);
        pk.y = f2bf_bits(ssp_f(acc[2])) | (f2bf_bits(ssp_f(acc[3])) << 16);
        *(uint2*)&s_tr1[w][16 * t + m][4 * g] = pk;
    }
    bf8 l1k[4];
    #pragma unroll
    for (int t = 0; t < 4; ++t)
        l1k[t] = (g < 2) ? *(const bf8*)&s_tr1[w][16 * t + m][8 * g] : zero_bf8();
    // --- layer1 v-net (reuse scratch; in-order DS pipe keeps reads-before-writes) ---
    #pragma unroll
    for (int t = 0; t < 4; ++t) {
        f32x4 acc = {b1v.x, b1v.y, b1v.z, b1v.w};
        acc = __builtin_amdgcn_mfma_f32_16x16x32_bf16(w1vf, eaf[t], acc, 0, 0, 0);
        uint2 pk;
        pk.x = f2bf_bits(ssp_f(acc[0])) | (f2bf_bits(ssp_f(acc[1])) << 16);
        pk.y = f2bf_bits(ssp_f(acc[2])) | (f2bf_bits(ssp_f(acc[3])) << 16);
        *(uint2*)&s_tr1[w][16 * t + m][4 * g] = pk;
    }
    bf8 l1v[4];
    #pragma unroll
    for (int t = 0; t < 4; ++t)
        l1v[t] = (g < 2) ? *(const bf8*)&s_tr1[w][16 * t + m][8 * g] : zero_bf8();

    // --- layer2 (K=16 zero-padded to 32): Wk/Wv[o][e] -> per-wave LDS ---
    #pragma unroll
    for (int t = 0; t < 4; ++t) {
        f32x4 acc = {b2k.x, b2k.y, b2k.z, b2k.w};
        acc = __builtin_amdgcn_mfma_f32_16x16x32_bf16(w2kf, l1k[t], acc, 0, 0, 0);
        uint2 pk;
        pk.x = f2bf_bits(acc[0]) | (f2bf_bits(acc[1]) << 16);
        pk.y = f2bf_bits(acc[2]) | (f2bf_bits(acc[3]) << 16);
        *(uint2*)&s_trk[w][16 * t + m][4 * g] = pk;

        f32x4 accv = {b2v.x, b2v.y, b2v.z, b2v.w};
        accv = __builtin_amdgcn_mfma_f32_16x16x32_bf16(w2vf, l1v[t], accv, 0, 0, 0);
        uint2 pv;
        pv.x = f2bf_bits(accv[0]) | (f2bf_bits(accv[1]) << 16);
        pv.y = f2bf_bits(accv[2]) | (f2bf_bits(accv[3]) << 16);
        *(uint2*)&s_trv[w][16 * t + m][4 * g] = pv;
    }

    // --- tail: 4 lanes per edge. Lane (g,m) handles head g of edge 16t+m.
    //     Each lane loads a 32B chunk of qt/hk/hv -> 4 lanes share a 128B row
    //     (16 distinct lines per VMEM instr instead of 64).
    #pragma unroll
    for (int t = 0; t < 4; ++t) {
        const int E = ebase + 16 * t + m;
        const int row = rcv[t].x, col = rcv[t].y;

        float Wk[16], Wv[16];
        unpack8(*(const uint4*)&s_trk[w][16 * t + m][0], Wk);
        unpack8(*(const uint4*)&s_trk[w][16 * t + m][8], Wk + 8);
        unpack8(*(const uint4*)&s_trv[w][16 * t + m][0], Wv);
        unpack8(*(const uint4*)&s_trv[w][16 * t + m][8], Wv + 8);

        const uint4* qp = (const uint4*)(qt + (size_t)row * HD + 16 * g);
        const uint4* kp = (const uint4*)(hk + (size_t)col * HD + 16 * g);
        const uint4* vp = (const uint4*)(hv + (size_t)col * HD + 16 * g);
        float qr[16], kc[16], vc[16];
        unpack8(qp[0], qr); unpack8(qp[1], qr + 8);
        unpack8(kp[0], kc); unpack8(kp[1], kc + 8);
        unpack8(vp[0], vc); unpack8(vp[1], vc + 8);

        // head g: channels 16g+i use Wk[i]/Wv[i] (edge nets broadcast over heads)
        float qk = qb[(size_t)row * NHEAD + g];
        #pragma unroll
        for (int i = 0; i < 16; ++i) qk += qr[i] * Wk[i] * kc[i];
        float wgt = __expf(qk);   // softmax shift-invariance

        float o[16];
        #pragma unroll
        for (int i = 0; i < 16; ++i) o[i] = wgt * Wv[i] * vc[i];
        uint4* pd = (uint4*)(payload + (size_t)E * HD + 16 * g);
        pd[0] = pack8u(o);
        pd[1] = pack8u(o + 8);
        wfac[(size_t)E * NHEAD + g] = wgt;   // contiguous 256B per instr
    }
}

// ---------------- Kernel E: streaming gather (8-edge groups) + finalize ----------------
__global__ __launch_bounds__(256) void gather_finalize_kernel(
    const float* __restrict__ x,
    const uint16_t* __restrict__ payload, const float* __restrict__ wfac,
    const int* __restrict__ offsets, const int* __restrict__ counts,
    const float* __restrict__ wvl_w, const float* __restrict__ wvl_b,
    const float* __restrict__ cen_w, const float* __restrict__ cen_b,
    const float* __restrict__ out_w, const float* __restrict__ out_b,
    float* __restrict__ out)
{
    // cen/out weights TRANSPOSED in LDS (2-way bank alias = free);
    // 64 nodes/block amortizes the 32KB staging 4x vs R4.
    __shared__ float s_cw[4096], s_ow[4096];
    __shared__ float s_wvl[256], s_vlb[16];
    __shared__ float s_m[4][64], s_x[4][64], s_t[4][64];
    for (int idx = threadIdx.x; idx < 4096; idx += 256) {
        int o = idx & 63, i = idx >> 6;
        s_cw[i * 64 + o] = cen_w[o * 64 + i];
        s_ow[i * 64 + o] = out_w[o * 64 + i];
    }
    if (threadIdx.x < 256) s_wvl[threadIdx.x] = wvl_w[threadIdx.x];
    if (threadIdx.x < 16) s_vlb[threadIdx.x] = wvl_b[threadIdx.x];
    __syncthreads();

    int l = threadIdx.x >> 6;   // wave id
    int L = threadIdx.x & 63;   // lane
    int q = L & 7;              // channel octet: channels 8q..8q+7
    int g = L >> 3;             // edge group 0..7
    int h = q >> 1;             // head owning the octet

    for (int t = 0; t < 16; ++t) {
        int n = blockIdx.x * 64 + l * 16 + t;
        bool valid = n < NN;
        int st = 0, deg = 0;
        if (valid) { st = offsets[n]; deg = counts[n]; }
        float u[8] = {0.f, 0.f, 0.f, 0.f, 0.f, 0.f, 0.f, 0.f};
        float ds = 0.f;
        const uint16_t* pp = payload + (size_t)st * HD + 8 * q;
        const float* wp = wfac + (size_t)st * NHEAD + h;
        int iters = (deg + 7) >> 3;
        for (int i = 0; i < iters; ++i) {
            int e = 8 * i + g;
            if (e < deg) {
                uint4 pv = *(const uint4*)(pp + (size_t)e * HD);  // 8 edges x 128B per wave-instr
                u[0] += bf2f(pv.x & 0xffffu); u[1] += bf2f(pv.x >> 16);
                u[2] += bf2f(pv.y & 0xffffu); u[3] += bf2f(pv.y >> 16);
                u[4] += bf2f(pv.z & 0xffffu); u[5] += bf2f(pv.z >> 16);
                u[6] += bf2f(pv.w & 0xffffu); u[7] += bf2f(pv.w >> 16);
                ds += wp[(size_t)e * NHEAD];
            }
        }
        // reduce over 8 edge-groups (xor lane bits 3,4,5 — head/channel bits preserved)
        #pragma unroll
        for (int s = 8; s < 64; s <<= 1) {
            #pragma unroll
            for (int j = 0; j < 8; ++j) u[j] += __shfl_xor(u[j], s);
            ds += __shfl_xor(ds, s);
        }
        if (g == 0) {
            float inv = (deg > 0) ? (1.f / ds) : 0.f;
            float r0[4] = {u[0] * inv, u[1] * inv, u[2] * inv, u[3] * inv};
            float r1[4] = {u[4] * inv, u[5] * inv, u[6] * inv, u[7] * inv};
            *(float4*)&s_m[l][8 * q] = *(float4*)r0;
            *(float4*)&s_m[l][8 * q + 4] = *(float4*)r1;
        }
        s_x[l][L] = valid ? x[(size_t)n * HD + L] : 0.f;
        // s_m/s_x/s_t rows are same-wave private: no __syncthreads needed

        int c = L, hh = c >> 4;
        float aggr = 0.f;
        if (deg > 0) {
            int o = c & 15;
            float s = s_vlb[o];
            #pragma unroll
            for (int i = 0; i < 16; ++i) s += s_m[l][hh * 16 + i] * s_wvl[o * 16 + i];
            aggr = s;
        }
        float sc = cen_b[c];
        #pragma unroll 8
        for (int i = 0; i < 64; ++i) sc += s_x[l][i] * s_cw[i * 64 + c];
        sc += aggr;
        s_t[l][c] = ssp_f(sc);
        float so = out_b[c];
        #pragma unroll 8
        for (int i = 0; i < 64; ++i) so += s_t[l][i] * s_ow[i * 64 + c];
        if (valid) out[(size_t)n * HD + c] = so;
    }
}

extern "C" void kernel_launch(void* const* d_in, const int* in_sizes, int n_in,
                              void* d_out, int out_size, void* d_ws, size_t ws_size,
                              hipStream_t stream)
{
    const float* x      = (const float*)d_in[0];
    const int*   ei     = (const int*)d_in[1];
    const float* ea     = (const float*)d_in[2];
    const float* k_w    = (const float*)d_in[3];
    const float* q_w    = (const float*)d_in[4];
    const float* v_w    = (const float*)d_in[5];
    const float* wkn_w1 = (const float*)d_in[6];
    const float* wkn_b1 = (const float*)d_in[7];
    const float* wkn_w2 = (const float*)d_in[8];
    const float* wkn_b2 = (const float*)d_in[9];
    const float* wkl_w  = (const float*)d_in[10];
    const float* wkl_b  = (const float*)d_in[11];
    const float* wvn_w1 = (const float*)d_in[12];
    const float* wvn_b1 = (const float*)d_in[13];
    const float* wvn_w2 = (const float*)d_in[14];
    const float* wvn_b2 = (const float*)d_in[15];
    const float* wvl_w  = (const float*)d_in[16];
    const float* wvl_b  = (const float*)d_in[17];
    const float* cen_w  = (const float*)d_in[18];
    const float* cen_b  = (const float*)d_in[19];
    const float* out_w  = (const float*)d_in[20];
    const float* out_b  = (const float*)d_in[21];
    float* out = (float*)d_out;

    // workspace layout (same as R4)
    float* qb    = (float*)d_ws;                              // NN*4 f32
    float* wfac  = qb + (size_t)NN * NHEAD;                   // NE*4 f32
    uint16_t* qt = (uint16_t*)(wfac + (size_t)NE * NHEAD);    // NN*64 bf16
    uint16_t* hk = qt + (size_t)NN * HD;                      // NN*64 bf16
    uint16_t* hv = hk + (size_t)NN * HD;                      // NN*64 bf16
    uint16_t* payload = hv + (size_t)NN * HD;                 // NE*64 bf16
    int2* rc     = (int2*)(payload + (size_t)NE * HD);        // NE int2
    int* elist   = (int*)(rc + (size_t)NE);                   // NE
    int* counts  = elist + NE;                                // NN
    int* bsum    = counts + NN;                               // 256
    int* offsets = bsum + 256;                                // NN
    int* cursor  = offsets + NN;                              // NN

    hipMemsetAsync(counts, 0, (size_t)NN * sizeof(int), stream);
    node_transform_kernel<<<NBLK, 256, 0, stream>>>(
        x, k_w, q_w, v_w, wkl_w, wkl_b, qt, qb, hk, hv);
    count_kernel<<<(NE + 255) / 256, 256, 0, stream>>>(ei, counts);
    scan_bsum_kernel<<<NBLK, 256, 0, stream>>>(counts, bsum);
    scan_top_kernel<<<1, 256, 0, stream>>>(bsum);
    scan_final_kernel<<<NBLK, 256, 0, stream>>>(counts, bsum, offsets, cursor);
    scatter_kernel<<<(NE + 255) / 256, 256, 0, stream>>>(ei, cursor, elist, rc);
    edge_compute_kernel<<<NE / 256, 256, 0, stream>>>(
        elist, rc, ea, wkn_w1, wkn_b1, wkn_w2, wkn_b2,
        wvn_w1, wvn_b1, wvn_w2, wvn_b2,
        qt, qb, hk, hv, payload, wfac);
    gather_finalize_kernel<<<(NN + 63) / 64, 256, 0, stream>>>(
        x, payload, wfac, offsets, counts,
        wvl_w, wvl_b, cen_w, cen_b, out_w, out_b, out);
}